// Round 1
// baseline (305.809 us; speedup 1.0000x reference)
//
#include <hip/hip_runtime.h>

typedef unsigned short u16;
typedef unsigned int   u32;
typedef unsigned long long u64;
typedef __bf16  bf16x8 __attribute__((ext_vector_type(8)));
typedef float   f32x4  __attribute__((ext_vector_type(4)));

// ---------- helpers ----------
__device__ __forceinline__ u16 f2bf(float f) {   // round-to-nearest-even
  u32 u = __builtin_bit_cast(u32, f);
  u += 0x7FFFu + ((u >> 16) & 1u);
  return (u16)(u >> 16);
}
__device__ __forceinline__ u32 pack2(float lo, float hi) {
  return (u32)f2bf(lo) | ((u32)f2bf(hi) << 16);
}

// async global->LDS, 16B per lane; LDS dest = wave-uniform base + lane*16
__device__ __forceinline__ void gload_lds16(const u16* g, u16* l) {
  __builtin_amdgcn_global_load_lds((const __attribute__((address_space(1))) void*)g,
                                   (__attribute__((address_space(3))) void*)l,
                                   16, 0, 0);
}

// ---------- prep: x fp32->bf16  AND  W fp32 -> bf16 transposed ----------
// grid (16,16,27): z<3 -> W-transpose (12x12 tiles of 64x64), z>=3 -> x cvt.
__global__ __launch_bounds__(256) void prep(const float* __restrict__ x,
                                            const float* __restrict__ w,
                                            u16* __restrict__ Xb,
                                            u16* __restrict__ Wt) {
  if (blockIdx.z < 3) {
    if (blockIdx.x >= 12 || blockIdx.y >= 12) return;
    __shared__ u16 t[64][65];
    const float* iz = w + (size_t)blockIdx.z * 768 * 768;
    u16* oz = Wt + (size_t)blockIdx.z * 768 * 768;
    const int tx = threadIdx.x & 63, ty = threadIdx.x >> 6;
    const int r0 = blockIdx.y * 64, c0 = blockIdx.x * 64;
#pragma unroll
    for (int rr = ty; rr < 64; rr += 4)
      t[rr][tx] = f2bf(iz[(size_t)(r0 + rr) * 768 + c0 + tx]);
    __syncthreads();
#pragma unroll
    for (int rr = ty; rr < 64; rr += 4)
      oz[(size_t)(c0 + rr) * 768 + r0 + tx] = t[tx][rr];
  } else {
    const size_t lin = (size_t)(blockIdx.z - 3) * 256 + blockIdx.y * 16 + blockIdx.x;
    const size_t i = lin * 256 + threadIdx.x;       // 8 elems per thread
    const float4* in4 = (const float4*)x;
    float4 a = in4[2 * i], b = in4[2 * i + 1];
    uint4 o;
    o.x = pack2(a.x, a.y); o.y = pack2(a.z, a.w);
    o.z = pack2(b.x, b.y); o.w = pack2(b.z, b.w);
    ((uint4*)Xb)[i] = o;
  }
}

// ---------- batched GEMM: C[m][n] = sum_k A[m][k] * Bt[n][k] ----------
// 256x256 tile, BK=64, 512 thr (8 waves, 2Mx4N), 128 KiB double-buffered LDS,
// 4-phase-per-K-tile schedule (T3+T4): per phase {ds_read quadrant ->
// raw s_barrier -> lgkmcnt(0) -> setprio(1) + 16 MFMA + setprio(0) -> barrier},
// next K-tile's 8 global_load_lds issued at phase 0, single vmcnt(0) per tile
// (issued ~4 phases after the loads -> effectively a counted wait, never a
// per-phase drain).  XOR chunk-swizzle on LDS (conflict-free, pre-swizzled
// global source since global_load_lds writes linearly).  XCD-aware block
// swizzle (all grids have nblk % 8 == 0).
// MODE 1: epilogue exp(acc/8) -> bf16 store + per-row sums -> lsum[bx][16384]
// MODE 2: epilogue scale by 1/rowsum (sums 8 partials), fp32 out
// MODE 3: fused QKV projection: n-split by 768 (= 3 x 256-tiles) -> Q|K plain
//         bf16 stores at strideC apart; V (matrix 2) stored TRANSPOSED via
//         LDS into vtp[b][768][2048]
template <int MODE, typename CT>
__global__ __launch_bounds__(512, 2)
void gemm_bt(const u16* __restrict__ A, const u16* __restrict__ B,
             CT* __restrict__ C, int Kd, int lda, int ldb, int ldc,
             size_t strideA, size_t strideB, size_t strideC,
             float* __restrict__ lsum, u16* __restrict__ vtp) {
  __shared__ __align__(16) u16 sh[2][2][256 * 64];   // [buf][A|B][256 rows x 64 k]

  // ---- XCD swizzle ----
  const u32 gx = gridDim.x, gy = gridDim.y;
  const u32 lin = blockIdx.x + gx * (blockIdx.y + gy * blockIdx.z);
  const u32 nblk = gx * gy * gridDim.z;
  const u32 newlin = (lin & 7u) * (nblk >> 3) + (lin >> 3);
  const u32 bx = newlin % gx;
  const u32 tmp = newlin / gx;
  const u32 by = tmp % gy;
  const u32 bz = tmp / gy;

  const u16* Az = A + (size_t)bz * strideA;
  const u16* Bz = B + (size_t)bz * strideB;
  const int m0 = by * 256;
  const int n0g = bx * 256;
  int n0 = n0g;
  int matrix = 0;
  CT* Cz;
  if (MODE == 3) {             // n-split store: matrix = n0/768 (768 = 3*256)
    matrix = n0g / 768;
    Cz = C + (size_t)matrix * strideC;
    n0 = n0g % 768;
  } else {
    Cz = C + (size_t)bz * strideC;
  }

  const int tid = threadIdx.x;
  const int lane = tid & 63, wave = tid >> 6;
  const int wr = wave >> 2, wc = wave & 3;          // 2 x 4 wave grid
  const int wm = wr * 128, wn = wc * 64;            // per-wave 128x64 output
  const int lr = lane & 15, quad = lane >> 4;
  const int sr = lane >> 3;                         // staging sub-row 0..7
  const int sc = ((lane & 7) ^ sr) << 3;            // pre-swizzled src element

  const u16* gA = Az + (size_t)m0 * lda;
  const u16* gB = Bz + (size_t)n0g * ldb;

  f32x4 acc[8][4] = {};
  const int NT = Kd >> 6;

  auto stage = [&](int buf, int k0) {               // 8 x global_load_lds / wave
#pragma unroll
    for (int r = 0; r < 4; ++r) {
      const int rows = r * 64 + wave * 8;
      gload_lds16(gA + (size_t)(rows + sr) * lda + (k0 + sc), &sh[buf][0][rows * 64]);
      gload_lds16(gB + (size_t)(rows + sr) * ldb + (k0 + sc), &sh[buf][1][rows * 64]);
    }
  };

  // prologue: tile 0 -> buf 0
  stage(0, 0);
  asm volatile("s_waitcnt vmcnt(0)" ::: "memory");
  __builtin_amdgcn_s_barrier();

  for (int t = 0; t < NT; ++t) {
    const char* sAc = (const char*)sh[t & 1][0];
    const char* sBc = (const char*)sh[t & 1][1];
    bf16x8 bq[4][2];                                // B frags held whole tile
#pragma unroll
    for (int p = 0; p < 4; ++p) {
      if (p == 0 && t + 1 < NT) stage((t + 1) & 1, (t + 1) << 6);
      bf16x8 aq[2][2];                              // A quadrant (mt = 2p, 2p+1)
#pragma unroll
      for (int mi = 0; mi < 2; ++mi)
#pragma unroll
        for (int kc = 0; kc < 2; ++kc)
          aq[mi][kc] = *(const bf16x8*)(sAc + (wm + (2 * p + mi) * 16 + lr) * 128 +
                                        ((((kc << 2) + quad) ^ (lr & 7)) << 4));
      if (p == 0) {
#pragma unroll
        for (int nt = 0; nt < 4; ++nt)
#pragma unroll
          for (int kc = 0; kc < 2; ++kc)
            bq[nt][kc] = *(const bf16x8*)(sBc + (wn + nt * 16 + lr) * 128 +
                                          ((((kc << 2) + quad) ^ (lr & 7)) << 4));
      }
      asm volatile("" ::: "memory");
      __builtin_amdgcn_s_barrier();
      asm volatile("s_waitcnt lgkmcnt(0)" ::: "memory");
      __builtin_amdgcn_sched_barrier(0);
      __builtin_amdgcn_s_setprio(1);
#pragma unroll
      for (int mi = 0; mi < 2; ++mi)
#pragma unroll
        for (int nt = 0; nt < 4; ++nt)
#pragma unroll
          for (int kc = 0; kc < 2; ++kc)
            acc[2 * p + mi][nt] = __builtin_amdgcn_mfma_f32_16x16x32_bf16(
                aq[mi][kc], bq[nt][kc], acc[2 * p + mi][nt], 0, 0, 0);
      __builtin_amdgcn_s_setprio(0);
      asm volatile("" ::: "memory");
      if (p < 3) __builtin_amdgcn_s_barrier();
    }
    // next tile's loads were issued 4 phases ago -> this wait is ~free
    asm volatile("s_waitcnt vmcnt(0)" ::: "memory");
    __builtin_amdgcn_s_barrier();
  }

  // ---- epilogues ----  C/D layout: col = lane&15, row = quad*4 + reg
  if (MODE == 1) {
    float* rowsum = (float*)sh;            // LDS reuse (post-barrier, drained)
    if (tid < 256) rowsum[tid] = 0.f;
    __syncthreads();
#pragma unroll
    for (int mt = 0; mt < 8; ++mt) {
#pragma unroll
      for (int i = 0; i < 4; ++i) {
        const int row_l = wm + mt * 16 + quad * 4 + i;
        CT* cp = Cz + (size_t)(m0 + row_l) * ldc + (n0 + wn + lr);
        float e[4], s = 0.f;
#pragma unroll
        for (int nt = 0; nt < 4; ++nt) {
          e[nt] = __expf(acc[mt][nt][i] * 0.125f);
          s += e[nt];
          cp[nt * 16] = f2bf(e[nt]);
        }
        s += __shfl_xor(s, 1);  s += __shfl_xor(s, 2);
        s += __shfl_xor(s, 4);  s += __shfl_xor(s, 8);   // 16-lane quad sum
        if (lr == 0) atomicAdd(&rowsum[row_l], s);
      }
    }
    __syncthreads();
    if (tid < 256)
      lsum[(size_t)bx * 16384 + (size_t)bz * 2048 + m0 + tid] = rowsum[tid];
  } else if (MODE == 2) {
    float* rinv = (float*)sh;              // LDS reuse (post-barrier, drained)
    if (tid < 256) {
      float s = 0.f;
      const size_t base = (size_t)bz * 2048 + m0 + tid;
#pragma unroll
      for (int xt = 0; xt < 8; ++xt) s += lsum[(size_t)xt * 16384 + base];
      rinv[tid] = 1.0f / s;
    }
    __syncthreads();
#pragma unroll
    for (int mt = 0; mt < 8; ++mt) {
#pragma unroll
      for (int i = 0; i < 4; ++i) {
        const int row_l = wm + mt * 16 + quad * 4 + i;
        const float iv = rinv[row_l];
        CT* cp = Cz + (size_t)(m0 + row_l) * ldc + (n0 + wn + lr);
#pragma unroll
        for (int nt = 0; nt < 4; ++nt) cp[nt * 16] = acc[mt][nt][i] * iv;
      }
    }
  } else if (MODE == 3 && matrix == 2) {
    // ---- V tile: store TRANSPOSED to vtp[b][o][t] via LDS ----
    // LDS phys: [col 0..255][row-group rg 0..63 XOR (col&63)][4 rows u16]
    u16* T = &sh[0][0][0];                 // 128 KB = full 256x256 u16 tile
#pragma unroll
    for (int mt = 0; mt < 8; ++mt) {
      const int rg = wr * 32 + mt * 4 + quad;          // row group (4 rows)
#pragma unroll
      for (int nt = 0; nt < 4; ++nt) {
        const int col = wn + nt * 16 + lr;
        u64 v = (u64)f2bf(acc[mt][nt][0])
              | ((u64)f2bf(acc[mt][nt][1]) << 16)
              | ((u64)f2bf(acc[mt][nt][2]) << 32)
              | ((u64)f2bf(acc[mt][nt][3]) << 48);
        *(u64*)((char*)T + col * 512 + ((rg ^ (col & 63)) << 3)) = v;
      }
    }
    __syncthreads();
    const int b = m0 >> 11;                // batch (256-row tile is within one)
#pragma unroll 4
    for (int it = 0; it < 32; ++it) {
      const int col = it * 8 + wave;
#pragma unroll
      for (int h = 0; h < 2; ++h) {
        const int rg = h * 32 + (lane >> 1);
        const u32 val = *(const u32*)((const char*)T + col * 512 +
                                      ((rg ^ (col & 63)) << 3) + ((lane & 1) << 2));
        *(u32*)(vtp + ((size_t)b * 768 + n0 + col) * 2048 +
                (m0 & 2047) + h * 128 + (lane << 1)) = val;
      }
    }
  } else {   // MODE 3 (Q/K) plain bf16 store
#pragma unroll
    for (int mt = 0; mt < 8; ++mt) {
#pragma unroll
      for (int i = 0; i < 4; ++i) {
        const int row_l = wm + mt * 16 + quad * 4 + i;
        CT* cp = Cz + (size_t)(m0 + row_l) * ldc + (n0 + wn + lr);
#pragma unroll
        for (int nt = 0; nt < 4; ++nt) cp[nt * 16] = f2bf(acc[mt][nt][i]);
      }
    }
  }
}

// ---------- launch ----------
extern "C" void kernel_launch(void* const* d_in, const int* in_sizes, int n_in,
                              void* d_out, int out_size, void* d_ws, size_t ws_size,
                              hipStream_t stream) {
  const float* x = (const float*)d_in[0];   // [8][2048][768]
  const float* w = (const float*)d_in[1];   // [3][768][768]
  float* out = (float*)d_out;               // [8][2048][768] fp32
  char* ws = (char*)d_ws;

  const size_t NS = (size_t)16384 * 768;
  // ws layout (bytes):
  //  [0, 67108864)              : Sc / P  bf16 [8][2048][2048]
  //    overlapped (dead before Sc is written):
  //    [0, 25165824)            : Xb bf16 [16384][768]
  //    [25165824, 28704768)     : Wt bf16 [2304][768]
  //  [67108864, 92274688)       : Q bf16 [16384][768]
  //  [92274688, 117440512)      : K bf16 [16384][768]
  //  [117440512, 118488832)     : Lpart fp32 [8][16384] (512 KB)
  //  [142606336, 167772160)     : Vt bf16 [8][768][2048]
  u16* Sc = (u16*)ws;
  u16* Xb = (u16*)ws;
  u16* Wt = (u16*)(ws + NS * 2);
  u16* Qm = (u16*)(ws + 67108864);
  float* Lpart = (float*)(ws + 117440512);
  u16* Vt = (u16*)(ws + 142606336);

  // 1) prep: x -> bf16; W -> bf16 transposed Wt[(i*768+o)][d]
  prep<<<dim3(16, 16, 27), 256, 0, stream>>>(x, w, Xb, Wt);
  // 2) fused QKV projection (single pass over Xb): Q,K plain; V -> Vt fused
  //    grid 9x64 = 576 blocks (%8==0)
  gemm_bt<3, u16><<<dim3(9, 64, 1), 512, 0, stream>>>(
      Xb, Wt, Qm, 768, 768, 768, 768, (size_t)0, (size_t)0, NS, Lpart, Vt);
  // 3) P = exp(Q K^T / 8) (bf16, unnormalized) + row partial sums -> Lpart
  //    grid 8x8x8 = 512 blocks
  gemm_bt<1, u16><<<dim3(8, 8, 8), 512, 0, stream>>>(
      Qm, Qm + NS, Sc, 768, 768, 768, 2048, (size_t)2048 * 768, (size_t)2048 * 768,
      (size_t)2048 * 2048, Lpart, nullptr);
  // 4) out = (P x V) / rowsum  (A=P [2048][2048], Bt=Vt [768][2048]) -> fp32
  //    grid 3x8x8 = 192 blocks
  gemm_bt<2, float><<<dim3(3, 8, 8), 512, 0, stream>>>(
      Sc, Vt, out, 2048, 2048, 2048, 768, (size_t)2048 * 2048,
      (size_t)768 * 2048, (size_t)2048 * 768, Lpart, nullptr);
}

// Round 2
// 291.954 us; speedup vs baseline: 1.0475x; 1.0475x over previous
//
#include <hip/hip_runtime.h>

typedef unsigned short u16;
typedef unsigned int   u32;
typedef unsigned long long u64;
typedef __bf16  bf16x8 __attribute__((ext_vector_type(8)));
typedef float   f32x4  __attribute__((ext_vector_type(4)));

// ---------- helpers ----------
__device__ __forceinline__ u16 f2bf(float f) {   // round-to-nearest-even
  u32 u = __builtin_bit_cast(u32, f);
  u += 0x7FFFu + ((u >> 16) & 1u);
  return (u16)(u >> 16);
}
__device__ __forceinline__ u32 pack2(float lo, float hi) {
  return (u32)f2bf(lo) | ((u32)f2bf(hi) << 16);
}

// async global->LDS, 16B per lane; LDS dest = wave-uniform base + lane*16
__device__ __forceinline__ void gload_lds16(const u16* g, u16* l) {
  __builtin_amdgcn_global_load_lds((const __attribute__((address_space(1))) void*)g,
                                   (__attribute__((address_space(3))) void*)l,
                                   16, 0, 0);
}

// ---------- prep: x fp32->bf16  AND  W fp32 -> bf16 transposed ----------
__global__ __launch_bounds__(256) void prep(const float* __restrict__ x,
                                            const float* __restrict__ w,
                                            u16* __restrict__ Xb,
                                            u16* __restrict__ Wt) {
  if (blockIdx.z < 3) {
    if (blockIdx.x >= 12 || blockIdx.y >= 12) return;
    __shared__ u16 t[64][65];
    const float* iz = w + (size_t)blockIdx.z * 768 * 768;
    u16* oz = Wt + (size_t)blockIdx.z * 768 * 768;
    const int tx = threadIdx.x & 63, ty = threadIdx.x >> 6;
    const int r0 = blockIdx.y * 64, c0 = blockIdx.x * 64;
#pragma unroll
    for (int rr = ty; rr < 64; rr += 4)
      t[rr][tx] = f2bf(iz[(size_t)(r0 + rr) * 768 + c0 + tx]);
    __syncthreads();
#pragma unroll
    for (int rr = ty; rr < 64; rr += 4)
      oz[(size_t)(c0 + rr) * 768 + r0 + tx] = t[tx][rr];
  } else {
    const size_t lin = (size_t)(blockIdx.z - 3) * 256 + blockIdx.y * 16 + blockIdx.x;
    const size_t i = lin * 256 + threadIdx.x;       // 8 elems per thread
    const float4* in4 = (const float4*)x;
    float4 a = in4[2 * i], b = in4[2 * i + 1];
    uint4 o;
    o.x = pack2(a.x, a.y); o.y = pack2(a.z, a.w);
    o.z = pack2(b.x, b.y); o.w = pack2(b.z, b.w);
    ((uint4*)Xb)[i] = o;
  }
}

// ---------- batched GEMM: C[m][n] = sum_k A[m][k] * Bt[n][k] ----------
// 256x256 tile, BK=64, 512 thr (8 waves, 2Mx4N), 128 KiB LDS.
// TRUE counted-vmcnt 8-phase pipeline (T3+T4):
//   buf0 holds even K-tiles, buf1 odd.  B-frags register-held from phase 1
//   (B-buffer frees after ph1 barrier); A-buffer frees after ph4 barrier.
//   One half-tile (2 gload_lds/thread) issued per phase:
//     ph1: A.h0(t+1)->Abuf1   ph2: A.h1(t+1)   ph3: B.h0(t+2)->Bbuf0
//     ph4: B.h1(t+2); vmcnt(4)+bar            ph5: A.h0(t+2)->Abuf0
//     ph6: A.h1(t+2)          ph7: B.h0(t+3)->Bbuf1  ph8: B.h1(t+3); vmcnt(4)
//   Every prefetch issued 3-6 phases before its consumer; never vmcnt(0)
//   in steady state; every LDS write-target freed by a barrier preceding
//   the issue (race-traced).  Last iteration: vmcnt(0) at ph4, no prefetch.
// MODE 1: epilogue exp(acc/8) -> bf16 store + per-row sums -> lsum[bx][16384]
// MODE 2: epilogue scale by 1/rowsum (sums 8 partials), fp32 out
// MODE 3: fused QKV: n-split by 768; Q|K plain stores; V stored TRANSPOSED
template <int MODE, typename CT>
__global__ __launch_bounds__(512, 2)
void gemm_bt(const u16* __restrict__ A, const u16* __restrict__ B,
             CT* __restrict__ C, int Kd, int lda, int ldb, int ldc,
             size_t strideA, size_t strideB, size_t strideC,
             float* __restrict__ lsum, u16* __restrict__ vtp) {
  __shared__ __align__(16) u16 sh[2][2][256 * 64];   // [buf][A|B][256 x 64]

  // ---- XCD swizzle ----
  const u32 gx = gridDim.x, gy = gridDim.y;
  const u32 lin = blockIdx.x + gx * (blockIdx.y + gy * blockIdx.z);
  const u32 nblk = gx * gy * gridDim.z;
  const u32 newlin = (lin & 7u) * (nblk >> 3) + (lin >> 3);
  const u32 bx = newlin % gx;
  const u32 tmp = newlin / gx;
  const u32 by = tmp % gy;
  const u32 bz = tmp / gy;

  const u16* Az = A + (size_t)bz * strideA;
  const u16* Bz = B + (size_t)bz * strideB;
  const int m0 = by * 256;
  const int n0g = bx * 256;
  int n0 = n0g;
  int matrix = 0;
  CT* Cz;
  if (MODE == 3) {             // n-split store: matrix = n0/768 (768 = 3*256)
    matrix = n0g / 768;
    Cz = C + (size_t)matrix * strideC;
    n0 = n0g % 768;
  } else {
    Cz = C + (size_t)bz * strideC;
  }

  const int tid = threadIdx.x;
  const int lane = tid & 63, wave = tid >> 6;
  const int wr = wave >> 2, wc = wave & 3;          // 2 x 4 wave grid
  const int wm = wr * 128, wn = wc * 64;            // per-wave 128x64 output
  const int lr = lane & 15, quad = lane >> 4;
  const int sr = lane >> 3;                         // staging sub-row 0..7
  const int sc = ((lane & 7) ^ sr) << 3;            // pre-swizzled src element

  const u16* gA = Az + (size_t)m0 * lda;
  const u16* gB = Bz + (size_t)n0g * ldb;

  f32x4 acc[8][4] = {};
  const int NT = Kd >> 6;
  const int NIT = NT >> 1;

  auto stageA = [&](int buf, int half, int k0) {    // one half-tile: 128 rows
#pragma unroll
    for (int r = 0; r < 2; ++r) {
      const int rows = half * 128 + r * 64 + wave * 8;
      gload_lds16(gA + (size_t)(rows + sr) * lda + (k0 + sc), &sh[buf][0][rows * 64]);
    }
  };
  auto stageB = [&](int buf, int half, int k0) {
#pragma unroll
    for (int r = 0; r < 2; ++r) {
      const int rows = half * 128 + r * 64 + wave * 8;
      gload_lds16(gB + (size_t)(rows + sr) * ldb + (k0 + sc), &sh[buf][1][rows * 64]);
    }
  };

  // ---- prologue: A(t0)+B(t0) -> buf0, B(t1) -> Bbuf1; wait first 4 stages
  stageA(0, 0, 0); stageA(0, 1, 0);
  stageB(0, 0, 0); stageB(0, 1, 0);
  stageB(1, 0, 64); stageB(1, 1, 64);
  asm volatile("s_waitcnt vmcnt(4)" ::: "memory");
  __builtin_amdgcn_s_barrier();

  for (int i = 0; i < NIT; ++i) {
    const bool full = (i + 1 < NIT);
    const int kA = (2 * i + 1) << 6;       // K-tile 2i+1 offset
    const int kN = (2 * i + 2) << 6;       // K-tile 2i+2
    const int kB2 = (2 * i + 3) << 6;      // K-tile 2i+3

    // ---- phases 1-4: tile 2i from buf0 ----
    {
      const char* sAc = (const char*)sh[0][0];
      const char* sBc = (const char*)sh[0][1];
      bf16x8 bq[4][2];
#pragma unroll
      for (int p = 0; p < 4; ++p) {
        bf16x8 aq[2][2];
#pragma unroll
        for (int mi = 0; mi < 2; ++mi)
#pragma unroll
          for (int kc = 0; kc < 2; ++kc)
            aq[mi][kc] = *(const bf16x8*)(sAc + (wm + (2 * p + mi) * 16 + lr) * 128 +
                                          ((((kc << 2) + quad) ^ (lr & 7)) << 4));
        if (p == 0) {
#pragma unroll
          for (int nt = 0; nt < 4; ++nt)
#pragma unroll
            for (int kc = 0; kc < 2; ++kc)
              bq[nt][kc] = *(const bf16x8*)(sBc + (wn + nt * 16 + lr) * 128 +
                                            ((((kc << 2) + quad) ^ (lr & 7)) << 4));
          stageA(1, 0, kA);
        } else if (p == 1) {
          stageA(1, 1, kA);
        } else if (p == 2) {
          if (full) stageB(0, 0, kN);
        } else {
          if (full) stageB(0, 1, kN);
        }
        __builtin_amdgcn_s_barrier();
        asm volatile("s_waitcnt lgkmcnt(0)" ::: "memory");
        __builtin_amdgcn_sched_barrier(0);
        __builtin_amdgcn_s_setprio(1);
#pragma unroll
        for (int mi = 0; mi < 2; ++mi)
#pragma unroll
          for (int nt = 0; nt < 4; ++nt)
#pragma unroll
            for (int kc = 0; kc < 2; ++kc)
              acc[2 * p + mi][nt] = __builtin_amdgcn_mfma_f32_16x16x32_bf16(
                  aq[mi][kc], bq[nt][kc], acc[2 * p + mi][nt], 0, 0, 0);
        __builtin_amdgcn_s_setprio(0);
        if (p < 3) __builtin_amdgcn_s_barrier();
      }
      if (full) asm volatile("s_waitcnt vmcnt(4)" ::: "memory");
      else      asm volatile("s_waitcnt vmcnt(0)" ::: "memory");
      __builtin_amdgcn_s_barrier();
    }

    // ---- phases 5-8: tile 2i+1 from buf1 ----
    {
      const char* sAc = (const char*)sh[1][0];
      const char* sBc = (const char*)sh[1][1];
      bf16x8 bq[4][2];
#pragma unroll
      for (int p = 0; p < 4; ++p) {
        bf16x8 aq[2][2];
#pragma unroll
        for (int mi = 0; mi < 2; ++mi)
#pragma unroll
          for (int kc = 0; kc < 2; ++kc)
            aq[mi][kc] = *(const bf16x8*)(sAc + (wm + (2 * p + mi) * 16 + lr) * 128 +
                                          ((((kc << 2) + quad) ^ (lr & 7)) << 4));
        if (p == 0) {
#pragma unroll
          for (int nt = 0; nt < 4; ++nt)
#pragma unroll
            for (int kc = 0; kc < 2; ++kc)
              bq[nt][kc] = *(const bf16x8*)(sBc + (wn + nt * 16 + lr) * 128 +
                                            ((((kc << 2) + quad) ^ (lr & 7)) << 4));
          if (full) stageA(0, 0, kN);
        } else if (p == 1) {
          if (full) stageA(0, 1, kN);
        } else if (p == 2) {
          if (full) stageB(1, 0, kB2);
        } else {
          if (full) stageB(1, 1, kB2);
        }
        __builtin_amdgcn_s_barrier();
        asm volatile("s_waitcnt lgkmcnt(0)" ::: "memory");
        __builtin_amdgcn_sched_barrier(0);
        __builtin_amdgcn_s_setprio(1);
#pragma unroll
        for (int mi = 0; mi < 2; ++mi)
#pragma unroll
          for (int nt = 0; nt < 4; ++nt)
#pragma unroll
            for (int kc = 0; kc < 2; ++kc)
              acc[2 * p + mi][nt] = __builtin_amdgcn_mfma_f32_16x16x32_bf16(
                  aq[mi][kc], bq[nt][kc], acc[2 * p + mi][nt], 0, 0, 0);
        __builtin_amdgcn_s_setprio(0);
        if (p < 3) __builtin_amdgcn_s_barrier();
      }
      if (full) asm volatile("s_waitcnt vmcnt(4)" ::: "memory");
      __builtin_amdgcn_s_barrier();
    }
  }

  // ---- epilogues ----  C/D layout: col = lane&15, row = quad*4 + reg
  if (MODE == 1) {
    float* rowsum = (float*)sh;            // LDS reuse (post-barrier, drained)
    if (tid < 256) rowsum[tid] = 0.f;
    __syncthreads();
#pragma unroll
    for (int mt = 0; mt < 8; ++mt) {
#pragma unroll
      for (int i = 0; i < 4; ++i) {
        const int row_l = wm + mt * 16 + quad * 4 + i;
        CT* cp = Cz + (size_t)(m0 + row_l) * ldc + (n0 + wn + lr);
        float e[4], s = 0.f;
#pragma unroll
        for (int nt = 0; nt < 4; ++nt) {
          e[nt] = __expf(acc[mt][nt][i] * 0.125f);
          s += e[nt];
          cp[nt * 16] = f2bf(e[nt]);
        }
        s += __shfl_xor(s, 1);  s += __shfl_xor(s, 2);
        s += __shfl_xor(s, 4);  s += __shfl_xor(s, 8);   // 16-lane quad sum
        if (lr == 0) atomicAdd(&rowsum[row_l], s);
      }
    }
    __syncthreads();
    if (tid < 256)
      lsum[(size_t)bx * 16384 + (size_t)bz * 2048 + m0 + tid] = rowsum[tid];
  } else if (MODE == 2) {
    float* rinv = (float*)sh;              // LDS reuse (post-barrier, drained)
    if (tid < 256) {
      float s = 0.f;
      const size_t base = (size_t)bz * 2048 + m0 + tid;
#pragma unroll
      for (int xt = 0; xt < 8; ++xt) s += lsum[(size_t)xt * 16384 + base];
      rinv[tid] = 1.0f / s;
    }
    __syncthreads();
#pragma unroll
    for (int mt = 0; mt < 8; ++mt) {
#pragma unroll
      for (int i = 0; i < 4; ++i) {
        const int row_l = wm + mt * 16 + quad * 4 + i;
        const float iv = rinv[row_l];
        CT* cp = Cz + (size_t)(m0 + row_l) * ldc + (n0 + wn + lr);
#pragma unroll
        for (int nt = 0; nt < 4; ++nt) cp[nt * 16] = acc[mt][nt][i] * iv;
      }
    }
  } else if (MODE == 3 && matrix == 2) {
    // ---- V tile: store TRANSPOSED to vtp[b][o][t] via LDS ----
    u16* T = &sh[0][0][0];                 // 128 KB = full 256x256 u16 tile
#pragma unroll
    for (int mt = 0; mt < 8; ++mt) {
      const int rg = wr * 32 + mt * 4 + quad;          // row group (4 rows)
#pragma unroll
      for (int nt = 0; nt < 4; ++nt) {
        const int col = wn + nt * 16 + lr;
        u64 v = (u64)f2bf(acc[mt][nt][0])
              | ((u64)f2bf(acc[mt][nt][1]) << 16)
              | ((u64)f2bf(acc[mt][nt][2]) << 32)
              | ((u64)f2bf(acc[mt][nt][3]) << 48);
        *(u64*)((char*)T + col * 512 + ((rg ^ (col & 63)) << 3)) = v;
      }
    }
    __syncthreads();
    const int b = m0 >> 11;                // batch (256-row tile is within one)
#pragma unroll 4
    for (int it = 0; it < 32; ++it) {
      const int col = it * 8 + wave;
#pragma unroll
      for (int h = 0; h < 2; ++h) {
        const int rg = h * 32 + (lane >> 1);
        const u32 val = *(const u32*)((const char*)T + col * 512 +
                                      ((rg ^ (col & 63)) << 3) + ((lane & 1) << 2));
        *(u32*)(vtp + ((size_t)b * 768 + n0 + col) * 2048 +
                (m0 & 2047) + h * 128 + (lane << 1)) = val;
      }
    }
  } else {   // MODE 3 (Q/K) plain bf16 store
#pragma unroll
    for (int mt = 0; mt < 8; ++mt) {
#pragma unroll
      for (int i = 0; i < 4; ++i) {
        const int row_l = wm + mt * 16 + quad * 4 + i;
        CT* cp = Cz + (size_t)(m0 + row_l) * ldc + (n0 + wn + lr);
#pragma unroll
        for (int nt = 0; nt < 4; ++nt) cp[nt * 16] = f2bf(acc[mt][nt][i]);
      }
    }
  }
}

// ---------- launch ----------
extern "C" void kernel_launch(void* const* d_in, const int* in_sizes, int n_in,
                              void* d_out, int out_size, void* d_ws, size_t ws_size,
                              hipStream_t stream) {
  const float* x = (const float*)d_in[0];   // [8][2048][768]
  const float* w = (const float*)d_in[1];   // [3][768][768]
  float* out = (float*)d_out;               // [8][2048][768] fp32
  char* ws = (char*)d_ws;

  const size_t NS = (size_t)16384 * 768;
  u16* Sc = (u16*)ws;
  u16* Xb = (u16*)ws;
  u16* Wt = (u16*)(ws + NS * 2);
  u16* Qm = (u16*)(ws + 67108864);
  float* Lpart = (float*)(ws + 117440512);
  u16* Vt = (u16*)(ws + 142606336);

  // 1) prep: x -> bf16; W -> bf16 transposed Wt[(i*768+o)][d]
  prep<<<dim3(16, 16, 27), 256, 0, stream>>>(x, w, Xb, Wt);
  // 2) fused QKV projection: grid 9x64 = 576 blocks (%8==0)
  gemm_bt<3, u16><<<dim3(9, 64, 1), 512, 0, stream>>>(
      Xb, Wt, Qm, 768, 768, 768, 768, (size_t)0, (size_t)0, NS, Lpart, Vt);
  // 3) P = exp(Q K^T / 8) + row partial sums: grid 8x8x8 = 512 blocks
  gemm_bt<1, u16><<<dim3(8, 8, 8), 512, 0, stream>>>(
      Qm, Qm + NS, Sc, 768, 768, 768, 2048, (size_t)2048 * 768, (size_t)2048 * 768,
      (size_t)2048 * 2048, Lpart, nullptr);
  // 4) out = (P x V) / rowsum: grid 3x8x8 = 192 blocks
  gemm_bt<2, float><<<dim3(3, 8, 8), 512, 0, stream>>>(
      Sc, Vt, out, 2048, 2048, 2048, 768, (size_t)2048 * 2048,
      (size_t)768 * 2048, (size_t)2048 * 768, Lpart, nullptr);
}